// Round 1
// baseline (249.427 us; speedup 1.0000x reference)
//
#include <hip/hip_runtime.h>
#include <hip/hip_bf16.h>

#define M_ROWS 8192
#define K_DIM 128
constexpr float INV_T = 5.0f;  // 1 / temperature

using f32x4 = __attribute__((ext_vector_type(4))) float;
using s16x8 = __attribute__((ext_vector_type(8))) short;

// ---------------- zero accumulators + output ----------------
__global__ __launch_bounds__(256) void kzero(float* __restrict__ acc, float* __restrict__ out) {
    int i = blockIdx.x * 256 + threadIdx.x;
    if (i < 3 * M_ROWS) acc[i] = 0.f;
    if (i == 0) out[0] = 0.f;
}

// ---------------- row L2-normalize, f32 -> bf16 ----------------
__global__ __launch_bounds__(256) void knorm(const float* __restrict__ feat, ushort* __restrict__ fn) {
    const int row = blockIdx.x * 4 + (threadIdx.x >> 6);
    const int lane = threadIdx.x & 63;
    const float2 v = *(const float2*)&feat[(size_t)row * K_DIM + lane * 2];
    float ss = v.x * v.x + v.y * v.y;
#pragma unroll
    for (int m = 1; m < 64; m <<= 1) ss += __shfl_xor(ss, m, 64);
    const float rn = rsqrtf(ss);
    __hip_bfloat16 ha = __float2bfloat16(v.x * rn);
    __hip_bfloat16 hb = __float2bfloat16(v.y * rn);
    ushort2 o;
    o.x = *reinterpret_cast<const ushort*>(&ha);
    o.y = *reinterpret_cast<const ushort*>(&hb);
    *(ushort2*)&fn[(size_t)row * K_DIM + lane * 2] = o;
}

// ---------------- fused sim-tile + reductions ----------------
// Tile 128x128 of C = fn * fn^T (sim = 5*dot). Per row i accumulate:
//   denom_i += sum_{j != i} exp(sim_ij)
//   psum_i  += sum_{j != i, label match} sim_ij
//   cnt_i   += count of label matches (j != i)
__global__ __launch_bounds__(256) void kmain(const ushort* __restrict__ fn,
                                             const int* __restrict__ labels,
                                             float* __restrict__ denom,
                                             float* __restrict__ psum,
                                             float* __restrict__ cnt) {
    __shared__ __align__(16) ushort lds[2 * 128 * 128];  // 64 KB: A tile | B tile
    ushort* ldsA = lds;
    ushort* ldsB = lds + 128 * 128;
    const int tid = threadIdx.x;
    const int brow = blockIdx.y * 128;
    const int bcol = blockIdx.x * 128;

    // Stage both tiles. 16B chunks; XOR-swizzle chunk index by (row&7) to kill
    // the 16-way bank conflict of the 256B-stride fragment reads.
#pragma unroll
    for (int it = 0; it < 8; ++it) {
        int c = it * 256 + tid;        // 2048 chunks per tile
        int row = c >> 4;              // 16 chunks (of 8 bf16) per row
        int ch = c & 15;
        int chs = ch ^ (row & 7);
        f32x4 va = *(const f32x4*)&fn[(size_t)(brow + row) * K_DIM + ch * 8];
        f32x4 vb = *(const f32x4*)&fn[(size_t)(bcol + row) * K_DIM + ch * 8];
        *(f32x4*)&ldsA[row * 128 + chs * 8] = va;
        *(f32x4*)&ldsB[row * 128 + chs * 8] = vb;
    }
    __syncthreads();

    const int w = tid >> 6;
    const int lane = tid & 63;
    const int wr = (w >> 1) * 64;   // wave quadrant row offset
    const int wc = (w & 1) * 64;    // wave quadrant col offset
    const int lrow = lane & 15;
    const int g = lane >> 4;

    f32x4 acc[4][4] = {};
#pragma unroll
    for (int kk = 0; kk < 4; ++kk) {  // K step = 32
        s16x8 af[4], bfr[4];
#pragma unroll
        for (int m = 0; m < 4; ++m) {
            int r = wr + m * 16 + lrow;
            int ch = (kk * 4 + g) ^ (r & 7);
            af[m] = *(const s16x8*)&ldsA[r * 128 + ch * 8];
        }
#pragma unroll
        for (int n = 0; n < 4; ++n) {
            int r = wc + n * 16 + lrow;
            int ch = (kk * 4 + g) ^ (r & 7);
            bfr[n] = *(const s16x8*)&ldsB[r * 128 + ch * 8];
        }
#pragma unroll
        for (int m = 0; m < 4; ++m)
#pragma unroll
            for (int n = 0; n < 4; ++n)
                acc[m][n] = __builtin_amdgcn_mfma_f32_16x16x32_bf16(af[m], bfr[n], acc[m][n], 0, 0, 0);
    }

    // Epilogue: C/D layout for 16x16x32: col = lane&15, row = (lane>>4)*4 + reg
    int gc[4], lc[4];
#pragma unroll
    for (int n = 0; n < 4; ++n) {
        gc[n] = bcol + wc + n * 16 + lrow;
        lc[n] = labels[gc[n]];
    }
#pragma unroll
    for (int m = 0; m < 4; ++m) {
#pragma unroll
        for (int r = 0; r < 4; ++r) {
            const int grow = brow + wr + m * 16 + g * 4 + r;
            const int lr = labels[grow];
            float pd = 0.f, pp = 0.f, pc = 0.f;
#pragma unroll
            for (int n = 0; n < 4; ++n) {
                float s = acc[m][n][r] * INV_T;
                float e = __expf(s);
                bool diag = (grow == gc[n]);
                if (diag) e = 0.f;
                pd += e;
                if (!diag && lr == lc[n]) { pp += s; pc += 1.f; }
            }
            // reduce across the 16 lanes sharing this output row
#pragma unroll
            for (int msk = 1; msk < 16; msk <<= 1) {
                pd += __shfl_xor(pd, msk, 16);
                pp += __shfl_xor(pp, msk, 16);
                pc += __shfl_xor(pc, msk, 16);
            }
            if (lrow == 0) {
                atomicAdd(&denom[grow], pd);
                atomicAdd(&psum[grow], pp);
                atomicAdd(&cnt[grow], pc);
            }
        }
    }
}

// ---------------- finalize: per-row loss, mean ----------------
__global__ __launch_bounds__(256) void kfin(const float* __restrict__ denom,
                                            const float* __restrict__ psum,
                                            const float* __restrict__ cnt,
                                            float* __restrict__ out) {
    const int i = blockIdx.x * 256 + threadIdx.x;
    const float c = cnt[i];
    const float d = fmaxf(denom[i], 1e-30f);
    float loss = (c * __logf(d) - psum[i]) / (c + 1.0f);
#pragma unroll
    for (int m = 1; m < 64; m <<= 1) loss += __shfl_xor(loss, m, 64);
    __shared__ float wsum[4];
    if ((threadIdx.x & 63) == 0) wsum[threadIdx.x >> 6] = loss;
    __syncthreads();
    if (threadIdx.x == 0)
        atomicAdd(out, (wsum[0] + wsum[1] + wsum[2] + wsum[3]) * (1.0f / M_ROWS));
}

extern "C" void kernel_launch(void* const* d_in, const int* in_sizes, int n_in,
                              void* d_out, int out_size, void* d_ws, size_t ws_size,
                              hipStream_t stream) {
    (void)in_sizes; (void)n_in; (void)out_size; (void)ws_size;
    const float* feat = (const float*)d_in[0];
    // d_in[1] (ious) unused: coef == 1
    const int* labels = (const int*)d_in[2];
    float* out = (float*)d_out;
    char* ws = (char*)d_ws;
    ushort* fn = (ushort*)ws;                                  // 8192*128 bf16 = 2 MB
    float* denom = (float*)(ws + (size_t)M_ROWS * K_DIM * 2);  // 3 * 32 KB accumulators
    float* psum = denom + M_ROWS;
    float* cnt = denom + 2 * M_ROWS;

    kzero<<<(3 * M_ROWS + 255) / 256, 256, 0, stream>>>(denom, out);
    knorm<<<M_ROWS / 4, 256, 0, stream>>>(feat, fn);
    dim3 grid(M_ROWS / 128, M_ROWS / 128);
    kmain<<<grid, 256, 0, stream>>>(fn, labels, denom, psum, cnt);
    kfin<<<M_ROWS / 256, 256, 0, stream>>>(denom, psum, cnt, out);
}

// Round 2
// 117.251 us; speedup vs baseline: 2.1273x; 2.1273x over previous
//
#include <hip/hip_runtime.h>
#include <hip/hip_bf16.h>

#define M_ROWS 8192
#define K_DIM 128
#define NCLS 60

// x = q_i . q_j where q = bf16(fhat * SCL), SCL^2 = 5*log2(e)  ->  sim = x*ln2, exp(sim) = 2^x
constexpr float SCL = 2.68579007f;     // sqrt(5 * 1.4426950408889634)
constexpr float LN2 = 0.69314718056f;

using f32x4 = __attribute__((ext_vector_type(4))) float;
using s16x8 = __attribute__((ext_vector_type(8))) short;

__device__ inline float bf2f(ushort u) {
    union { unsigned int i; float f; } v; v.i = ((unsigned int)u) << 16; return v.f;
}
__device__ inline float fexp2(float x) {
#if __has_builtin(__builtin_amdgcn_exp2f)
    return __builtin_amdgcn_exp2f(x);
#else
    return exp2f(x);
#endif
}

// ws float region: denom[8192] | S[60*128 -> 7680] | cntC[64]
#define NZERO (M_ROWS + NCLS * K_DIM + 64)

__global__ __launch_bounds__(256) void kinit(float* __restrict__ z, float* __restrict__ out) {
    int i = blockIdx.x * 256 + threadIdx.x;
    if (i < NZERO) z[i] = 0.f;
    if (i == 0) out[0] = 0.f;
}

// ---------------- row L2-normalize, scale, f32 -> bf16 ----------------
__global__ __launch_bounds__(256) void knorm(const float* __restrict__ feat, ushort* __restrict__ fn) {
    const int row = blockIdx.x * 4 + (threadIdx.x >> 6);
    const int lane = threadIdx.x & 63;
    const float2 v = *(const float2*)&feat[(size_t)row * K_DIM + lane * 2];
    float ss = v.x * v.x + v.y * v.y;
#pragma unroll
    for (int m = 1; m < 64; m <<= 1) ss += __shfl_xor(ss, m, 64);
    const float rs = rsqrtf(ss) * SCL;
    __hip_bfloat16 ha = __float2bfloat16(v.x * rs);
    __hip_bfloat16 hb = __float2bfloat16(v.y * rs);
    ushort2 o;
    o.x = *reinterpret_cast<const ushort*>(&ha);
    o.y = *reinterpret_cast<const ushort*>(&hb);
    *(ushort2*)&fn[(size_t)row * K_DIM + lane * 2] = o;
}

// ---------------- class sums S_c[k] and class counts ----------------
__global__ __launch_bounds__(256) void kclass(const ushort* __restrict__ fn,
                                              const int* __restrict__ labels,
                                              float* __restrict__ S, float* __restrict__ cntC) {
    const int c = blockIdx.x;           // class
    const int tid = threadIdx.x;
    const int k = tid & 127;
    int j = blockIdx.y * 1024 + (tid >> 7);
    float s = 0.f, cnt = 0.f;
    for (int it = 0; it < 512; ++it, j += 2) {
        if (labels[j] == c) { s += bf2f(fn[(size_t)j * K_DIM + k]); cnt += 1.f; }
    }
    atomicAdd(&S[c * K_DIM + k], s);
    if (tid == 0 || tid == 128) atomicAdd(&cntC[c], cnt);
}

// ---------------- main: denom_i = sum_j 2^(q_i.q_j) (incl diag) ----------------
// Block: 256 rows (4 waves x 64), loops over 4 col-tiles of 128. A-frags in regs.
__global__ __launch_bounds__(256) void kmain(const ushort* __restrict__ fn,
                                             float* __restrict__ denom) {
    __shared__ __align__(16) ushort ldsB[2][128 * K_DIM];  // 2 x 32 KB double buffer
    const int tid = threadIdx.x;
    const int lane = tid & 63;
    const int lrow = lane & 15;
    const int g = lane >> 4;
    const int browW = blockIdx.x * 256 + (tid >> 6) * 64;  // this wave's first row
    const int cg = blockIdx.y;

    // persistent A fragments: af[m][kk] covers rows browW..+63, K=128
    s16x8 af[4][4];
#pragma unroll
    for (int m = 0; m < 4; ++m)
#pragma unroll
        for (int kk = 0; kk < 4; ++kk)
            af[m][kk] = *(const s16x8*)&fn[(size_t)(browW + m * 16 + lrow) * K_DIM + kk * 32 + g * 8];

    float pd[4][4] = {};  // row partial denoms: row = m*16 + g*4 + r, summed over this thread's cols

    // async stage of one 128-col tile: LDS linear dest, inverse-swizzled global source.
    // LDS[cr][c] holds global chunk (c ^ (cr&7)) of row cr  (chunk = 8 bf16 = 16B)
    auto stage = [&](int buf, int t) {
        const ushort* gb = fn + (size_t)(cg * 4 + t) * 128 * K_DIM;
#pragma unroll
        for (int it = 0; it < 8; ++it) {
            const int p = it * 256 + tid;        // chunk id 0..2047
            const int cr = p >> 4, cc = p & 15;
            const ushort* gsrc = gb + cr * K_DIM + ((cc ^ (cr & 7)) * 8);
            ushort* ldst = &ldsB[buf][(size_t)(it * 256 + (tid & 192)) * 8];  // wave-uniform base
            __builtin_amdgcn_global_load_lds((const __attribute__((address_space(1))) void*)gsrc,
                                             (__attribute__((address_space(3))) void*)ldst, 16, 0, 0);
        }
    };

    stage(0, 0);
#pragma unroll
    for (int t = 0; t < 4; ++t) {
        __syncthreads();                 // barrier drains vmcnt -> buf[t&1] ready
        if (t < 3) stage((t + 1) & 1, t + 1);   // in flight during compute
        const ushort* buf = ldsB[t & 1];
#pragma unroll
        for (int h = 0; h < 2; ++h) {    // 64-col halves
            f32x4 acc[4][4] = {};
#pragma unroll
            for (int kk = 0; kk < 4; ++kk) {
                s16x8 bfr[4];
#pragma unroll
                for (int n = 0; n < 4; ++n) {
                    const int cr = (h * 4 + n) * 16 + lrow;
                    const int cc = (kk * 4 + g) ^ (cr & 7);
                    bfr[n] = *(const s16x8*)&buf[cr * K_DIM + cc * 8];
                }
#pragma unroll
                for (int m = 0; m < 4; ++m)
#pragma unroll
                    for (int n = 0; n < 4; ++n)
                        acc[m][n] = __builtin_amdgcn_mfma_f32_16x16x32_bf16(af[m][kk], bfr[n], acc[m][n], 0, 0, 0);
            }
#pragma unroll
            for (int m = 0; m < 4; ++m)
#pragma unroll
                for (int n = 0; n < 4; ++n)
#pragma unroll
                    for (int r = 0; r < 4; ++r)
                        pd[m][r] += fexp2(acc[m][n][r]);
        }
    }

    // one reduction per row at block end: sum over the 16 column-lanes
#pragma unroll
    for (int m = 0; m < 4; ++m)
#pragma unroll
        for (int r = 0; r < 4; ++r) {
            float v = pd[m][r];
#pragma unroll
            for (int msk = 1; msk < 16; msk <<= 1) v += __shfl_xor(v, msk, 16);
            if (lrow == 0) atomicAdd(&denom[browW + m * 16 + g * 4 + r], v);
        }
}

// ---------------- finalize: per-row loss, mean ----------------
__global__ __launch_bounds__(1024) void kfin(const ushort* __restrict__ fn,
                                             const int* __restrict__ labels,
                                             const float* __restrict__ denom,
                                             const float* __restrict__ S,
                                             const float* __restrict__ cntC,
                                             float* __restrict__ out) {
    const int tid = threadIdx.x;
    const int wv = tid >> 6, lane = tid & 63;
    const int row = blockIdx.x * 16 + wv;
    const ushort2 qv = *(const ushort2*)&fn[(size_t)row * K_DIM + lane * 2];
    const float f0 = bf2f(qv.x), f1 = bf2f(qv.y);
    const int c = labels[row];
    const float2 sv = *(const float2*)&S[c * K_DIM + lane * 2];
    float dot = f0 * sv.x + f1 * sv.y;   // q_i . S_c  (includes self)
    float sii = f0 * f0 + f1 * f1;       // q_i . q_i
#pragma unroll
    for (int msk = 1; msk < 64; msk <<= 1) {
        dot += __shfl_xor(dot, msk, 64);
        sii += __shfl_xor(sii, msk, 64);
    }
    __shared__ float ls[16];
    if (lane == 0) {
        const float cf = cntC[c];                                   // count incl. self
        const float d = fmaxf(denom[row] - fexp2(sii), 1e-5f);      // exclude diagonal
        const float p = (dot - sii) * LN2;                          // sum of matched sims, excl diag
        ls[wv] = ((cf - 1.f) * __logf(d) - p) / cf;
    }
    __syncthreads();
    if (tid == 0) {
        float s = 0.f;
#pragma unroll
        for (int i = 0; i < 16; ++i) s += ls[i];
        atomicAdd(out, s * (1.0f / M_ROWS));
    }
}

extern "C" void kernel_launch(void* const* d_in, const int* in_sizes, int n_in,
                              void* d_out, int out_size, void* d_ws, size_t ws_size,
                              hipStream_t stream) {
    (void)in_sizes; (void)n_in; (void)out_size; (void)ws_size;
    const float* feat = (const float*)d_in[0];
    const int* labels = (const int*)d_in[2];   // d_in[1] (ious) unused: coef == 1
    float* out = (float*)d_out;
    char* ws = (char*)d_ws;
    ushort* fn = (ushort*)ws;                                   // 2 MB bf16 features
    float* denom = (float*)(ws + (size_t)M_ROWS * K_DIM * 2);
    float* S = denom + M_ROWS;
    float* cntC = S + NCLS * K_DIM;

    kinit<<<(NZERO + 255) / 256, 256, 0, stream>>>(denom, out);
    knorm<<<M_ROWS / 4, 256, 0, stream>>>(feat, fn);
    kclass<<<dim3(NCLS, 8), 256, 0, stream>>>(fn, labels, S, cntC);
    kmain<<<dim3(M_ROWS / 256, 16), 256, 0, stream>>>(fn, denom);
    kfin<<<M_ROWS / 16, 1024, 0, stream>>>(fn, labels, denom, S, cntC, out);
}

// Round 3
// 91.326 us; speedup vs baseline: 2.7312x; 1.2839x over previous
//
#include <hip/hip_runtime.h>
#include <hip/hip_bf16.h>

#define M_ROWS 8192
#define K_DIM 128
#define NCLS 60

// x = q_i . q_j where q = bf16(fhat * SCL), SCL^2 = 5*log2(e)  ->  sim = x*ln2, exp(sim) = 2^x
constexpr float SCL = 2.68579007f;     // sqrt(5 * 1.4426950408889634)
constexpr float LN2 = 0.69314718056f;

using f32x4 = __attribute__((ext_vector_type(4))) float;
using s16x8 = __attribute__((ext_vector_type(8))) short;

__device__ inline float bf2f(ushort u) {
    union { unsigned int i; float f; } v; v.i = ((unsigned int)u) << 16; return v.f;
}
__device__ inline float fexp2(float x) { return exp2f(x); }

// ws float region: denom[8192] | S[60*128] | cntC[64]
#define NZERO (M_ROWS + NCLS * K_DIM + 64)

__global__ __launch_bounds__(256) void kinit(float* __restrict__ z, float* __restrict__ out) {
    int i = blockIdx.x * 256 + threadIdx.x;
    if (i < NZERO) z[i] = 0.f;
    if (i == 0) out[0] = 0.f;
}

// ---------------- row L2-normalize, scale, f32 -> bf16 ----------------
__global__ __launch_bounds__(256) void knorm(const float* __restrict__ feat, ushort* __restrict__ fn) {
    const int row = blockIdx.x * 4 + (threadIdx.x >> 6);
    const int lane = threadIdx.x & 63;
    const float2 v = *(const float2*)&feat[(size_t)row * K_DIM + lane * 2];
    float ss = v.x * v.x + v.y * v.y;
#pragma unroll
    for (int m = 1; m < 64; m <<= 1) ss += __shfl_xor(ss, m, 64);
    const float rs = rsqrtf(ss) * SCL;
    __hip_bfloat16 ha = __float2bfloat16(v.x * rs);
    __hip_bfloat16 hb = __float2bfloat16(v.y * rs);
    ushort2 o;
    o.x = *reinterpret_cast<const ushort*>(&ha);
    o.y = *reinterpret_cast<const ushort*>(&hb);
    *(ushort2*)&fn[(size_t)row * K_DIM + lane * 2] = o;
}

// ---------------- class sums: single pass, LDS-privatized ----------------
__global__ __launch_bounds__(256) void kclass(const ushort* __restrict__ fn,
                                              const int* __restrict__ labels,
                                              float* __restrict__ S, float* __restrict__ cntC) {
    __shared__ float Sl[NCLS * K_DIM];   // 30 KB private class-sum table
    __shared__ float Cl[NCLS];
    const int tid = threadIdx.x;
    for (int i = tid; i < NCLS * K_DIM; i += 256) Sl[i] = 0.f;
    if (tid < NCLS) Cl[tid] = 0.f;
    __syncthreads();

    const int rsub = tid >> 4;           // 16 rows concurrent
    const int kc = tid & 15;             // 16 lanes per row
    const int rbase = blockIdx.x * 128;
#pragma unroll
    for (int it = 0; it < 8; ++it) {
        const int row = rbase + it * 16 + rsub;
        const int lab = labels[row];
        if (kc == 0) atomicAdd(&Cl[lab], 1.f);
#pragma unroll
        for (int j = 0; j < 4; ++j) {
            const int k0 = j * 32 + kc * 2;   // ushort2-strided: <=4-way LDS bank alias
            const ushort2 q = *(const ushort2*)&fn[(size_t)row * K_DIM + k0];
            atomicAdd(&Sl[lab * K_DIM + k0], bf2f(q.x));
            atomicAdd(&Sl[lab * K_DIM + k0 + 1], bf2f(q.y));
        }
    }
    __syncthreads();
    for (int i = tid; i < NCLS * K_DIM; i += 256) atomicAdd(&S[i], Sl[i]);
    if (tid < NCLS) atomicAdd(&cntC[tid], Cl[tid]);
}

// ---------------- main: denom_i = sum_j 2^(q_i.q_j) (incl diag), symmetric ----------------
// Upper-triangle 256x256 blocks: block (I,J), I<=J. Off-diag blocks add each exp2
// to its row sum (rows of I) AND col sum (rows of J).
__global__ __launch_bounds__(256) void kmain(const ushort* __restrict__ fn,
                                             float* __restrict__ denom) {
    __shared__ __align__(16) ushort ldsB[2][128 * K_DIM];  // 2 x 32 KB double buffer
    const int tid = threadIdx.x;
    const int lane = tid & 63;
    const int lrow = lane & 15;
    const int g = lane >> 4;

    // decode blockIdx.x -> (I, J), I <= J < 32; off(I) = 32I - I(I-1)/2
    const int bid = blockIdx.x;
    int I = (int)((65.0f - sqrtf(65.0f * 65.0f - 8.0f * (float)bid)) * 0.5f);
    while ((I + 1) * 32 - ((I + 1) * I) / 2 <= bid) ++I;
    while (I * 32 - (I * (I - 1)) / 2 > bid) --I;
    const int J = I + (bid - (I * 32 - (I * (I - 1)) / 2));
    const bool offd = (J != I);

    const int browW = I * 256 + (tid >> 6) * 64;   // this wave's first A row

    // async stage of one 128-col tile of panel J: LDS linear dest, inverse-swizzled source.
    // LDS[cr][c] holds global chunk (c ^ (cr&7)) of row cr (chunk = 8 bf16 = 16B)
    auto stage = [&](int buf, int t) {
        const ushort* gb = fn + (size_t)(J * 256 + t * 128) * K_DIM;
#pragma unroll
        for (int it = 0; it < 8; ++it) {
            const int p = it * 256 + tid;
            const int cr = p >> 4, cc = p & 15;
            const ushort* gsrc = gb + cr * K_DIM + ((cc ^ (cr & 7)) * 8);
            ushort* ldst = &ldsB[buf][(size_t)(it * 256 + (tid & 192)) * 8];
            __builtin_amdgcn_global_load_lds((const __attribute__((address_space(1))) void*)gsrc,
                                             (__attribute__((address_space(3))) void*)ldst, 16, 0, 0);
        }
    };

    stage(0, 0);

    // persistent A fragments: rows browW..+63, K=128
    s16x8 af[4][4];
#pragma unroll
    for (int m = 0; m < 4; ++m)
#pragma unroll
        for (int kk = 0; kk < 4; ++kk)
            af[m][kk] = *(const s16x8*)&fn[(size_t)(browW + m * 16 + lrow) * K_DIM + kk * 32 + g * 8];

    float pd[4][4] = {};  // per-thread row partials

#pragma unroll
    for (int t = 0; t < 2; ++t) {
        __syncthreads();                  // barrier drains vmcnt -> buf[t] ready
        if (t == 0) stage(1, 1);
        const ushort* buf = ldsB[t];
#pragma unroll
        for (int h = 0; h < 2; ++h) {     // 64-col halves
            f32x4 acc[4][4] = {};
#pragma unroll
            for (int kk = 0; kk < 4; ++kk) {
                s16x8 bfr[4];
#pragma unroll
                for (int n = 0; n < 4; ++n) {
                    const int cr = (h * 4 + n) * 16 + lrow;
                    const int cc = (kk * 4 + g) ^ (cr & 7);
                    bfr[n] = *(const s16x8*)&buf[cr * K_DIM + cc * 8];
                }
#pragma unroll
                for (int m = 0; m < 4; ++m)
#pragma unroll
                    for (int n = 0; n < 4; ++n)
                        acc[m][n] = __builtin_amdgcn_mfma_f32_16x16x32_bf16(af[m][kk], bfr[n], acc[m][n], 0, 0, 0);
            }
            float pcn[4] = {0.f, 0.f, 0.f, 0.f};  // per-thread col partials (this half)
#pragma unroll
            for (int m = 0; m < 4; ++m)
#pragma unroll
                for (int n = 0; n < 4; ++n)
#pragma unroll
                    for (int r = 0; r < 4; ++r) {
                        const float e = fexp2(acc[m][n][r]);
                        pd[m][r] += e;
                        pcn[n] += e;
                    }
            if (offd) {
#pragma unroll
                for (int n = 0; n < 4; ++n) {
                    float v = pcn[n];
                    v += __shfl_xor(v, 16);
                    v += __shfl_xor(v, 32);
                    if (lane < 16)
                        atomicAdd(&denom[J * 256 + t * 128 + h * 64 + n * 16 + lrow], v);
                }
            }
        }
    }

    // row sums: reduce across the 16 column-lanes
#pragma unroll
    for (int m = 0; m < 4; ++m)
#pragma unroll
        for (int r = 0; r < 4; ++r) {
            float v = pd[m][r];
#pragma unroll
            for (int msk = 1; msk < 16; msk <<= 1) v += __shfl_xor(v, msk, 16);
            if (lrow == 0) atomicAdd(&denom[browW + m * 16 + g * 4 + r], v);
        }
}

// ---------------- finalize: per-row loss, mean ----------------
__global__ __launch_bounds__(1024) void kfin(const ushort* __restrict__ fn,
                                             const int* __restrict__ labels,
                                             const float* __restrict__ denom,
                                             const float* __restrict__ S,
                                             const float* __restrict__ cntC,
                                             float* __restrict__ out) {
    const int tid = threadIdx.x;
    const int wv = tid >> 6, lane = tid & 63;
    const int row = blockIdx.x * 16 + wv;
    const ushort2 qv = *(const ushort2*)&fn[(size_t)row * K_DIM + lane * 2];
    const float f0 = bf2f(qv.x), f1 = bf2f(qv.y);
    const int c = labels[row];
    const float2 sv = *(const float2*)&S[c * K_DIM + lane * 2];
    float dot = f0 * sv.x + f1 * sv.y;   // q_i . S_c  (includes self)
    float sii = f0 * f0 + f1 * f1;       // q_i . q_i
#pragma unroll
    for (int msk = 1; msk < 64; msk <<= 1) {
        dot += __shfl_xor(dot, msk, 64);
        sii += __shfl_xor(sii, msk, 64);
    }
    __shared__ float ls[16];
    if (lane == 0) {
        const float cf = cntC[c];                                   // count incl. self
        const float d = fmaxf(denom[row] - fexp2(sii), 1e-5f);      // exclude diagonal
        const float p = (dot - sii) * LN2;                          // matched sims, excl diag
        ls[wv] = ((cf - 1.f) * __logf(d) - p) / cf;
    }
    __syncthreads();
    if (tid == 0) {
        float s = 0.f;
#pragma unroll
        for (int i = 0; i < 16; ++i) s += ls[i];
        atomicAdd(out, s * (1.0f / M_ROWS));
    }
}

extern "C" void kernel_launch(void* const* d_in, const int* in_sizes, int n_in,
                              void* d_out, int out_size, void* d_ws, size_t ws_size,
                              hipStream_t stream) {
    (void)in_sizes; (void)n_in; (void)out_size; (void)ws_size;
    const float* feat = (const float*)d_in[0];
    const int* labels = (const int*)d_in[2];   // d_in[1] (ious) unused: coef == 1
    float* out = (float*)d_out;
    char* ws = (char*)d_ws;
    ushort* fn = (ushort*)ws;                                   // 2 MB bf16 features
    float* denom = (float*)(ws + (size_t)M_ROWS * K_DIM * 2);
    float* S = denom + M_ROWS;
    float* cntC = S + NCLS * K_DIM;

    kinit<<<(NZERO + 255) / 256, 256, 0, stream>>>(denom, out);
    knorm<<<M_ROWS / 4, 256, 0, stream>>>(feat, fn);
    kclass<<<M_ROWS / 128, 256, 0, stream>>>(fn, labels, S, cntC);
    kmain<<<528, 256, 0, stream>>>(fn, denom);
    kfin<<<M_ROWS / 16, 1024, 0, stream>>>(fn, labels, denom, S, cntC, out);
}